// Round 5
// baseline (275.889 us; speedup 1.0000x reference)
//
#include <hip/hip_runtime.h>
#include <math.h>

#define NB 4
#define NC 256
#define NHEADS 4
#define DH 64
#define NT 4096            // 64*64 tokens per batch
#define SCALE 0.125f
// q pre-scale with log2(e) folded in: exp(s/8) == exp2(s * QSCALE)
#define QSCALE (0.125f * 1.44269504088896f)

typedef __bf16  bf16x8 __attribute__((ext_vector_type(8)));
typedef float   f32x4  __attribute__((ext_vector_type(4)));
typedef short   s16x8  __attribute__((ext_vector_type(8)));
typedef short   s16x4  __attribute__((ext_vector_type(4)));

static __device__ __forceinline__ unsigned short f2bf(float f) {
    unsigned u = __float_as_uint(f);
    u = (u + 0x7fffu + ((u >> 16) & 1u)) >> 16;   // round-to-nearest-even
    return (unsigned short)u;
}

// Stage 64 rows x 256 bf16 (global row stride 256 elems) -> LDS stride 264.
static __device__ __forceinline__ void stage_64x256(
    unsigned short* __restrict__ lds, const unsigned short* __restrict__ g, int tid)
{
    #pragma unroll
    for (int chunk = 0; chunk < 8; ++chunk) {
        const int row = chunk * 8 + (tid >> 5);
        const int col = (tid & 31) * 8;
        *(s16x8*)&lds[row * 264 + col] = *(const s16x8*)&g[row * 256 + col];
    }
}

// ---------------------------------------------------------------------------
// Kernel 0: weight prep (unchanged).
// ---------------------------------------------------------------------------
__global__ __launch_bounds__(256) void k_prep(
    const float* __restrict__ wqkv, const float* __restrict__ wproj,
    unsigned short* __restrict__ wqkv_t, unsigned short* __restrict__ wproj_bf)
{
    const int id = blockIdx.x;
    const int tid = threadIdx.x;
    if (id < 48) {
        __shared__ float T[64][65];
        const int jt = id % 12, ct = id / 12;
        #pragma unroll
        for (int p = 0; p < 16; ++p) {
            const int idx = tid + (p << 8);
            const int r = idx >> 6, cl = idx & 63;
            T[r][cl] = wqkv[(size_t)(ct * 64 + r) * 768 + jt * 64 + cl];
        }
        __syncthreads();
        #pragma unroll
        for (int p = 0; p < 16; ++p) {
            const int idx = tid + (p << 8);
            const int r = idx >> 6, cl = idx & 63;
            wqkv_t[(size_t)(jt * 64 + r) * 256 + ct * 64 + cl] = f2bf(T[cl][r]);
        }
    } else {
        const int base = (id - 48) * 2048 + tid * 8;
        s16x8 v;
        #pragma unroll
        for (int j = 0; j < 8; ++j) v[j] = (short)f2bf(wproj[base + j]);
        *(s16x8*)&wproj_bf[base] = v;
    }
}

// ---------------------------------------------------------------------------
// Kernel 1: LayerNorm + QKV GEMM via bf16 MFMA. (q scale now QSCALE)
// ---------------------------------------------------------------------------
__global__ __launch_bounds__(256) void k_ln_qkv(
    const float* __restrict__ x,       // [B][C][N]
    const float* __restrict__ ln_g,
    const float* __restrict__ ln_b,
    const unsigned short* __restrict__ wqkv_t,  // [768][256] bf16
    unsigned short* __restrict__ q_bf,
    unsigned short* __restrict__ k_bf,
    unsigned short* __restrict__ v_bf)
{
    __shared__ unsigned short An[64 * 264];
    __shared__ unsigned short Wt[64 * 264];
    __shared__ float red1[4][64], red2[4][64];
    __shared__ float mu_s[64], rs_s[64];

    const int b     = blockIdx.x >> 6;
    const int n0    = (blockIdx.x & 63) << 6;
    const int three = blockIdx.y;
    const int tid   = threadIdx.x;
    const int li    = tid & 63;
    const int grp   = tid >> 6;
    const int w     = grp;
    const int lane  = li;
    const int q4    = lane >> 4;
    const int c     = lane & 15;

    const float* xb = x + ((size_t)b * NC) * NT + n0 + li;

    float s1 = 0.f, s2 = 0.f;
    for (int cc = 0; cc < 64; ++cc) {
        const int ch = (cc << 2) + grp;
        const float v = xb[(size_t)ch * NT];
        s1 += v; s2 += v * v;
    }
    red1[grp][li] = s1; red2[grp][li] = s2;
    __syncthreads();
    if (tid < 64) {
        const float t1 = red1[0][tid] + red1[1][tid] + red1[2][tid] + red1[3][tid];
        const float t2 = red2[0][tid] + red2[1][tid] + red2[2][tid] + red2[3][tid];
        const float mu  = t1 * (1.0f / NC);
        const float var = t2 * (1.0f / NC) - mu * mu;
        mu_s[tid] = mu;
        rs_s[tid] = rsqrtf(var + 1e-5f);
    }
    __syncthreads();
    const float mu = mu_s[li];
    const float rs = rs_s[li];

    #pragma unroll
    for (int chunk = 0; chunk < 8; ++chunk) {
        s16x8 pk;
        #pragma unroll
        for (int j = 0; j < 8; ++j) {
            const int ch = chunk * 32 + grp * 8 + j;
            const float vv = (xb[(size_t)ch * NT] - mu) * rs * ln_g[ch] + ln_b[ch];
            pk[j] = (short)f2bf(vv);
        }
        *(s16x8*)&An[li * 264 + chunk * 32 + grp * 8] = pk;
    }
    __syncthreads();

    bf16x8 aT[8];
    if (three < 2) {
        #pragma unroll
        for (int kt = 0; kt < 8; ++kt)
            aT[kt] = *(const bf16x8*)&An[(16 * w + c) * 264 + kt * 32 + q4 * 8];
    }

    for (int jt = 0; jt < 4; ++jt) {
        __syncthreads();
        stage_64x256(Wt, wqkv_t + (size_t)(three * 256 + jt * 64) * 256, tid);
        __syncthreads();

        f32x4 acc[4];
        #pragma unroll
        for (int nt = 0; nt < 4; ++nt)
            #pragma unroll
            for (int r = 0; r < 4; ++r) acc[nt][r] = 0.f;

        const int bh = b * NHEADS + jt;
        if (three < 2) {
            #pragma unroll
            for (int nt = 0; nt < 4; ++nt)
                #pragma unroll
                for (int kt = 0; kt < 8; ++kt) {
                    const bf16x8 bb = *(const bf16x8*)&Wt[(16 * nt + c) * 264 + kt * 32 + q4 * 8];
                    acc[nt] = __builtin_amdgcn_mfma_f32_16x16x32_bf16(aT[kt], bb, acc[nt], 0, 0, 0);
                }
            unsigned short* dst = (three == 0 ? q_bf : k_bf) + ((size_t)bh * NT + n0) * DH;
            const float sc = (three == 0) ? QSCALE : 1.0f;
            #pragma unroll
            for (int nt = 0; nt < 4; ++nt)
                #pragma unroll
                for (int r = 0; r < 4; ++r)
                    dst[(size_t)(16 * w + 4 * q4 + r) * DH + 16 * nt + c] = f2bf(acc[nt][r] * sc);
        } else {
            bf16x8 aW[8];
            #pragma unroll
            for (int kt = 0; kt < 8; ++kt)
                aW[kt] = *(const bf16x8*)&Wt[(16 * w + c) * 264 + kt * 32 + q4 * 8];
            #pragma unroll
            for (int nt = 0; nt < 4; ++nt)
                #pragma unroll
                for (int kt = 0; kt < 8; ++kt) {
                    const bf16x8 bb = *(const bf16x8*)&An[(16 * nt + c) * 264 + kt * 32 + q4 * 8];
                    acc[nt] = __builtin_amdgcn_mfma_f32_16x16x32_bf16(aW[kt], bb, acc[nt], 0, 0, 0);
                }
            unsigned short* dst = v_bf + (size_t)bh * DH * NT;
            #pragma unroll
            for (int nt = 0; nt < 4; ++nt)
                #pragma unroll
                for (int r = 0; r < 4; ++r)
                    dst[(size_t)(16 * w + 4 * q4 + r) * NT + n0 + 16 * nt + c] = f2bf(acc[nt][r]);
        }
    }
}

// ---------------------------------------------------------------------------
// Kernel 2: split-K bf16-MFMA flash attention. Each block: 128 queries x
// 2048 keys (half the K range). Unnormalized partial O (f32) + l partials
// to workspace; max-free softmax via exp2 (scale folded into q).
// grid = 16 bh * 32 qtiles * 2 khalf = 1024 blocks -> 4 blocks/CU.
// LDS: Ks 9216 + Vt 9216 + Ps(bf16 128x76) 19456 = 37888 B.
// ---------------------------------------------------------------------------
__global__ __launch_bounds__(256, 4) void k_attn(
    const unsigned short* __restrict__ qg,  // [bh][n][d], pre-scaled by QSCALE
    const unsigned short* __restrict__ kg,  // [bh][n][d]
    const unsigned short* __restrict__ vg,  // [bh][d][n]  (transposed)
    float* __restrict__ o_part,             // [2][16][4096][64] f32
    float* __restrict__ l_part)             // [2][16][4096] f32
{
    __shared__ unsigned short Ks[64 * 72];
    __shared__ unsigned short Vt[64 * 72];
    __shared__ unsigned short Ps[128 * 76];

    const int bh   = blockIdx.x >> 6;          // 0..15
    const int rest = blockIdx.x & 63;
    const int qt   = rest >> 1;                // 0..31
    const int kh   = rest & 1;                 // K half
    const int n0   = qt << 7;                  // 128-query tile base
    const int kt0  = kh << 5;                  // first 64-key tile index
    const int tid  = threadIdx.x;
    const int w    = tid >> 6;                 // wave -> query rows 32w..32w+31
    const int lane = tid & 63;
    const int q4   = lane >> 4;
    const int c    = lane & 15;

    const unsigned short* kb = kg + (size_t)bh * NT * DH;
    const unsigned short* vb = vg + (size_t)bh * DH * NT;

    // ---- Q A-frags direct from global ----
    bf16x8 aq[2][2];
    {
        const unsigned short* qp = qg + ((size_t)bh * NT + n0) * DH;
        #pragma unroll
        for (int g = 0; g < 2; ++g) {
            const unsigned short* qrow = qp + (size_t)(32 * w + 16 * g + c) * DH;
            aq[g][0] = *(const bf16x8*)(qrow + q4 * 8);
            aq[g][1] = *(const bf16x8*)(qrow + 32 + q4 * 8);
        }
    }

    // staging geometry: id in [0,512): row = id>>3, oct = id&7 (16B chunks)
    const int r0 = tid >> 3, oc0 = (tid & 7) * 8;
    const int r1 = (tid + 256) >> 3, oc1 = oc0;

    s16x8 pk0, pk1, pv0, pv1;
    {
        const unsigned short* kp = kb + (size_t)(kt0 << 6) * DH;
        const unsigned short* vp = vb + (kt0 << 6);
        pk0 = *(const s16x8*)&kp[(size_t)r0 * DH + oc0];
        pk1 = *(const s16x8*)&kp[(size_t)r1 * DH + oc1];
        pv0 = *(const s16x8*)&vp[(size_t)r0 * NT + oc0];
        pv1 = *(const s16x8*)&vp[(size_t)r1 * NT + oc1];
    }
    *(s16x8*)&Ks[r0 * 72 + oc0] = pk0;
    *(s16x8*)&Ks[r1 * 72 + oc1] = pk1;
    *(s16x8*)&Vt[r0 * 72 + oc0] = pv0;
    *(s16x8*)&Vt[r1 * 72 + oc1] = pv1;

    f32x4 oac[2][4];
    #pragma unroll
    for (int g = 0; g < 2; ++g)
        #pragma unroll
        for (int dt = 0; dt < 4; ++dt)
            #pragma unroll
            for (int r = 0; r < 4; ++r) oac[g][dt][r] = 0.f;
    float l_r[2][4] = {};

    for (int it = 0; it < 32; ++it) {
        __syncthreads();                        // Ks/Vt writes visible

        if (it < 31) {
            const unsigned short* kp = kb + (size_t)((kt0 + it + 1) << 6) * DH;
            const unsigned short* vp = vb + ((kt0 + it + 1) << 6);
            pk0 = *(const s16x8*)&kp[(size_t)r0 * DH + oc0];
            pk1 = *(const s16x8*)&kp[(size_t)r1 * DH + oc1];
            pv0 = *(const s16x8*)&vp[(size_t)r0 * NT + oc0];
            pv1 = *(const s16x8*)&vp[(size_t)r1 * NT + oc1];
        }

        // ---- S = Q K^T for both row groups (K frags shared) ----
        f32x4 s[2][4];
        #pragma unroll
        for (int nt = 0; nt < 4; ++nt) {
            const bf16x8 b0 = *(const bf16x8*)&Ks[(16 * nt + c) * 72 + q4 * 8];
            const bf16x8 b1 = *(const bf16x8*)&Ks[(16 * nt + c) * 72 + 32 + q4 * 8];
            #pragma unroll
            for (int g = 0; g < 2; ++g) {
                f32x4 acc;
                #pragma unroll
                for (int r = 0; r < 4; ++r) acc[r] = 0.f;
                acc = __builtin_amdgcn_mfma_f32_16x16x32_bf16(aq[g][0], b0, acc, 0, 0, 0);
                acc = __builtin_amdgcn_mfma_f32_16x16x32_bf16(aq[g][1], b1, acc, 0, 0, 0);
                s[g][nt] = acc;
            }
        }

        // ---- P = exp2(S) (scale*log2e folded into q); l partials in regs ----
        #pragma unroll
        for (int g = 0; g < 2; ++g)
            #pragma unroll
            for (int nt = 0; nt < 4; ++nt)
                #pragma unroll
                for (int r = 0; r < 4; ++r) {
                    const float e = exp2f(s[g][nt][r]);
                    l_r[g][r] += e;
                    Ps[(32 * w + 16 * g + 4 * q4 + r) * 76 + 16 * nt + c] = f2bf(e);
                }

        // ---- PV (V frags shared across groups) ----
        bf16x8 pa[2][2];
        #pragma unroll
        for (int g = 0; g < 2; ++g) {
            const unsigned short* prow = &Ps[(32 * w + 16 * g + c) * 76];
            pa[g][0] = *(const bf16x8*)(prow + q4 * 8);
            pa[g][1] = *(const bf16x8*)(prow + 32 + q4 * 8);
        }
        #pragma unroll
        for (int dt = 0; dt < 4; ++dt) {
            const bf16x8 v0 = *(const bf16x8*)&Vt[(16 * dt + c) * 72 + q4 * 8];
            const bf16x8 v1 = *(const bf16x8*)&Vt[(16 * dt + c) * 72 + 32 + q4 * 8];
            #pragma unroll
            for (int g = 0; g < 2; ++g) {
                oac[g][dt] = __builtin_amdgcn_mfma_f32_16x16x32_bf16(pa[g][0], v0, oac[g][dt], 0, 0, 0);
                oac[g][dt] = __builtin_amdgcn_mfma_f32_16x16x32_bf16(pa[g][1], v1, oac[g][dt], 0, 0, 0);
            }
        }

        __syncthreads();                        // all Ks/Vt reads done

        if (it < 31) {
            *(s16x8*)&Ks[r0 * 72 + oc0] = pk0;
            *(s16x8*)&Ks[r1 * 72 + oc1] = pk1;
            *(s16x8*)&Vt[r0 * 72 + oc0] = pv0;
            *(s16x8*)&Vt[r1 * 72 + oc1] = pv1;
        }
    }

    // ---- write unnormalized partial O (f32) and l partial ----
    float* op = o_part + (((size_t)kh * 16 + bh) * NT + n0 + 32 * w) * DH;
    #pragma unroll
    for (int g = 0; g < 2; ++g)
        #pragma unroll
        for (int dt = 0; dt < 4; ++dt)
            #pragma unroll
            for (int r = 0; r < 4; ++r)
                op[(size_t)(16 * g + 4 * q4 + r) * DH + 16 * dt + c] = oac[g][dt][r];

    // per-row l: reduce across the 16 column-lanes, lane c==0 stores
    float* lp = l_part + ((size_t)kh * 16 + bh) * NT + n0 + 32 * w;
    #pragma unroll
    for (int g = 0; g < 2; ++g)
        #pragma unroll
        for (int r = 0; r < 4; ++r) {
            float t = l_r[g][r];
            t += __shfl_xor(t, 1);
            t += __shfl_xor(t, 2);
            t += __shfl_xor(t, 4);
            t += __shfl_xor(t, 8);
            if (c == 0) lp[16 * g + 4 * q4 + r] = t;
        }
}

// ---------------------------------------------------------------------------
// Kernel 2b: combine the two K-halves: O = (O0+O1)/(l0+l1), store bf16
// into [B][N][C]. grid = 16 bh * 32 qtiles = 512 blocks, 256 threads.
// ---------------------------------------------------------------------------
__global__ __launch_bounds__(256) void k_combine(
    const float* __restrict__ o_part,   // [2][16][4096][64]
    const float* __restrict__ l_part,   // [2][16][4096]
    unsigned short* __restrict__ o)     // [B][N][256] bf16
{
    const int bh   = blockIdx.x >> 5;
    const int n0   = (blockIdx.x & 31) << 7;
    const int b    = bh >> 2;
    const int head = bh & 3;
    const int tid  = threadIdx.x;
    const int row  = tid >> 1;            // 0..127
    const int c0   = (tid & 1) * 32;

    const float l0 = l_part[(size_t)bh * NT + n0 + row];
    const float l1 = l_part[(size_t)(16 + bh) * NT + n0 + row];
    const float rinv = 1.0f / (l0 + l1);

    const float* p0 = o_part + ((size_t)bh * NT + n0 + row) * DH + c0;
    const float* p1 = o_part + ((size_t)(16 + bh) * NT + n0 + row) * DH + c0;
    unsigned short* dst = o + ((size_t)b * NT + n0 + row) * NC + head * DH + c0;

    #pragma unroll
    for (int j = 0; j < 8; ++j) {
        const f32x4 a = *(const f32x4*)(p0 + j * 4);
        const f32x4 bb = *(const f32x4*)(p1 + j * 4);
        s16x4 v;
        #pragma unroll
        for (int e = 0; e < 4; ++e) v[e] = (short)f2bf((a[e] + bb[e]) * rinv);
        *(s16x4*)(dst + j * 4) = v;
    }
}

// ---------------------------------------------------------------------------
// Kernel 3: output projection via bf16 MFMA. (unchanged)
// ---------------------------------------------------------------------------
__global__ __launch_bounds__(256) void k_proj(
    const unsigned short* __restrict__ o_bf,     // [B][N][256] bf16
    const unsigned short* __restrict__ wproj_bf, // [256][256] bf16
    const float* __restrict__ b_proj,
    float* __restrict__ out)                     // [B][C][N]
{
    __shared__ unsigned short Os[64 * 264];
    __shared__ unsigned short Ws[64 * 264];

    const int b   = blockIdx.x >> 6;
    const int n0  = (blockIdx.x & 63) << 6;
    const int cg0 = blockIdx.y << 6;
    const int tid = threadIdx.x;
    const int w   = tid >> 6;
    const int lane = tid & 63;
    const int q4  = lane >> 4;
    const int c   = lane & 15;

    stage_64x256(Os, o_bf + ((size_t)b * NT + n0) * NC, tid);
    stage_64x256(Ws, wproj_bf + (size_t)cg0 * NC, tid);
    __syncthreads();

    bf16x8 a[8];
    #pragma unroll
    for (int kt = 0; kt < 8; ++kt)
        a[kt] = *(const bf16x8*)&Ws[(16 * w + c) * 264 + kt * 32 + q4 * 8];

    f32x4 acc[4];
    #pragma unroll
    for (int nt = 0; nt < 4; ++nt)
        #pragma unroll
        for (int r = 0; r < 4; ++r) acc[nt][r] = 0.f;

    #pragma unroll
    for (int nt = 0; nt < 4; ++nt)
        #pragma unroll
        for (int kt = 0; kt < 8; ++kt) {
            const bf16x8 bb = *(const bf16x8*)&Os[(16 * nt + c) * 264 + kt * 32 + q4 * 8];
            acc[nt] = __builtin_amdgcn_mfma_f32_16x16x32_bf16(a[kt], bb, acc[nt], 0, 0, 0);
        }

    #pragma unroll
    for (int nt = 0; nt < 4; ++nt)
        #pragma unroll
        for (int r = 0; r < 4; ++r) {
            const int cg = cg0 + 16 * w + 4 * q4 + r;
            out[((size_t)b * NC + cg) * NT + n0 + 16 * nt + c] = acc[nt][r] + b_proj[cg];
        }
}

// ---------------------------------------------------------------------------
extern "C" void kernel_launch(void* const* d_in, const int* in_sizes, int n_in,
                              void* d_out, int out_size, void* d_ws, size_t ws_size,
                              hipStream_t stream)
{
    const float* x      = (const float*)d_in[0];
    const float* ln_g   = (const float*)d_in[1];
    const float* ln_b   = (const float*)d_in[2];
    const float* w_qkv  = (const float*)d_in[3];
    const float* w_proj = (const float*)d_in[4];
    const float* b_proj = (const float*)d_in[5];
    float* out = (float*)d_out;

    const size_t TEN = (size_t)NB * NHEADS * NT * DH;   // 4,194,304 elements

    // f32 region first (alignment), then bf16 region.
    float* ws32 = (float*)d_ws;
    float* o_part = ws32;                                // 2*16*4096*64 = 8,388,608 f32
    float* l_part = ws32 + 8388608;                      // 131,072 f32
    unsigned short* ws16 = (unsigned short*)(l_part + 131072);
    unsigned short* q_bf    = ws16;
    unsigned short* k_bf    = ws16 + TEN;
    unsigned short* v_bf    = ws16 + 2 * TEN;
    unsigned short* wqkv_t  = ws16 + 3 * TEN;            // [768][256]
    unsigned short* wproj_b = wqkv_t + 768 * 256;        // [256][256]
    unsigned short* o_bf    = q_bf;                      // alias: q dead after k_attn

    k_prep<<<80, 256, 0, stream>>>(w_qkv, w_proj, wqkv_t, wproj_b);
    k_ln_qkv<<<dim3(NB * 64, 3), 256, 0, stream>>>(x, ln_g, ln_b, wqkv_t, q_bf, k_bf, v_bf);
    k_attn<<<16 * 64, 256, 0, stream>>>(q_bf, k_bf, v_bf, o_part, l_part);
    k_combine<<<16 * 32, 256, 0, stream>>>(o_part, l_part, o_bf);
    k_proj<<<dim3(NB * 64, 4), 256, 0, stream>>>(o_bf, wproj_b, b_proj, out);
}

// Round 6
// 239.717 us; speedup vs baseline: 1.1509x; 1.1509x over previous
//
#include <hip/hip_runtime.h>
#include <math.h>

#define NB 4
#define NC 256
#define NHEADS 4
#define DH 64
#define NT 4096            // 64*64 tokens per batch
// q pre-scale with log2(e) folded in: exp(s/8) == exp2(s * QSCALE)
#define QSCALE (0.125f * 1.44269504088896f)

typedef __bf16  bf16x8 __attribute__((ext_vector_type(8)));
typedef float   f32x4  __attribute__((ext_vector_type(4)));
typedef short   s16x8  __attribute__((ext_vector_type(8)));

static __device__ __forceinline__ unsigned short f2bf(float f) {
    unsigned u = __float_as_uint(f);
    u = (u + 0x7fffu + ((u >> 16) & 1u)) >> 16;   // round-to-nearest-even
    return (unsigned short)u;
}

// async 16B/lane global -> LDS (DMA, no VGPR round-trip). LDS dest is
// wave-uniform base + lane*16; global src is per-lane.
static __device__ __forceinline__ void gload16(const unsigned short* g, unsigned short* l) {
    __builtin_amdgcn_global_load_lds((const __attribute__((address_space(1))) void*)g,
                                     (__attribute__((address_space(3))) void*)l, 16, 0, 0);
}

// Stage 64 rows x 256 bf16 (global row stride 256 elems) -> LDS stride 264.
static __device__ __forceinline__ void stage_64x256(
    unsigned short* __restrict__ lds, const unsigned short* __restrict__ g, int tid)
{
    #pragma unroll
    for (int chunk = 0; chunk < 8; ++chunk) {
        const int row = chunk * 8 + (tid >> 5);
        const int col = (tid & 31) * 8;
        *(s16x8*)&lds[row * 264 + col] = *(const s16x8*)&g[row * 256 + col];
    }
}

// ---------------------------------------------------------------------------
// Kernel 0: weight prep (unchanged).
// ---------------------------------------------------------------------------
__global__ __launch_bounds__(256) void k_prep(
    const float* __restrict__ wqkv, const float* __restrict__ wproj,
    unsigned short* __restrict__ wqkv_t, unsigned short* __restrict__ wproj_bf)
{
    const int id = blockIdx.x;
    const int tid = threadIdx.x;
    if (id < 48) {
        __shared__ float T[64][65];
        const int jt = id % 12, ct = id / 12;
        #pragma unroll
        for (int p = 0; p < 16; ++p) {
            const int idx = tid + (p << 8);
            const int r = idx >> 6, cl = idx & 63;
            T[r][cl] = wqkv[(size_t)(ct * 64 + r) * 768 + jt * 64 + cl];
        }
        __syncthreads();
        #pragma unroll
        for (int p = 0; p < 16; ++p) {
            const int idx = tid + (p << 8);
            const int r = idx >> 6, cl = idx & 63;
            wqkv_t[(size_t)(jt * 64 + r) * 256 + ct * 64 + cl] = f2bf(T[cl][r]);
        }
    } else {
        const int base = (id - 48) * 2048 + tid * 8;
        s16x8 v;
        #pragma unroll
        for (int j = 0; j < 8; ++j) v[j] = (short)f2bf(wproj[base + j]);
        *(s16x8*)&wproj_bf[base] = v;
    }
}

// ---------------------------------------------------------------------------
// Kernel 1: LayerNorm + QKV GEMM via bf16 MFMA. (unchanged from R5)
// ---------------------------------------------------------------------------
__global__ __launch_bounds__(256) void k_ln_qkv(
    const float* __restrict__ x,       // [B][C][N]
    const float* __restrict__ ln_g,
    const float* __restrict__ ln_b,
    const unsigned short* __restrict__ wqkv_t,  // [768][256] bf16
    unsigned short* __restrict__ q_bf,
    unsigned short* __restrict__ k_bf,
    unsigned short* __restrict__ v_bf)
{
    __shared__ unsigned short An[64 * 264];
    __shared__ unsigned short Wt[64 * 264];
    __shared__ float red1[4][64], red2[4][64];
    __shared__ float mu_s[64], rs_s[64];

    const int b     = blockIdx.x >> 6;
    const int n0    = (blockIdx.x & 63) << 6;
    const int three = blockIdx.y;
    const int tid   = threadIdx.x;
    const int li    = tid & 63;
    const int grp   = tid >> 6;
    const int w     = grp;
    const int lane  = li;
    const int q4    = lane >> 4;
    const int c     = lane & 15;

    const float* xb = x + ((size_t)b * NC) * NT + n0 + li;

    float s1 = 0.f, s2 = 0.f;
    for (int cc = 0; cc < 64; ++cc) {
        const int ch = (cc << 2) + grp;
        const float v = xb[(size_t)ch * NT];
        s1 += v; s2 += v * v;
    }
    red1[grp][li] = s1; red2[grp][li] = s2;
    __syncthreads();
    if (tid < 64) {
        const float t1 = red1[0][tid] + red1[1][tid] + red1[2][tid] + red1[3][tid];
        const float t2 = red2[0][tid] + red2[1][tid] + red2[2][tid] + red2[3][tid];
        const float mu  = t1 * (1.0f / NC);
        const float var = t2 * (1.0f / NC) - mu * mu;
        mu_s[tid] = mu;
        rs_s[tid] = rsqrtf(var + 1e-5f);
    }
    __syncthreads();
    const float mu = mu_s[li];
    const float rs = rs_s[li];

    #pragma unroll
    for (int chunk = 0; chunk < 8; ++chunk) {
        s16x8 pk;
        #pragma unroll
        for (int j = 0; j < 8; ++j) {
            const int ch = chunk * 32 + grp * 8 + j;
            const float vv = (xb[(size_t)ch * NT] - mu) * rs * ln_g[ch] + ln_b[ch];
            pk[j] = (short)f2bf(vv);
        }
        *(s16x8*)&An[li * 264 + chunk * 32 + grp * 8] = pk;
    }
    __syncthreads();

    bf16x8 aT[8];
    if (three < 2) {
        #pragma unroll
        for (int kt = 0; kt < 8; ++kt)
            aT[kt] = *(const bf16x8*)&An[(16 * w + c) * 264 + kt * 32 + q4 * 8];
    }

    for (int jt = 0; jt < 4; ++jt) {
        __syncthreads();
        stage_64x256(Wt, wqkv_t + (size_t)(three * 256 + jt * 64) * 256, tid);
        __syncthreads();

        f32x4 acc[4];
        #pragma unroll
        for (int nt = 0; nt < 4; ++nt)
            #pragma unroll
            for (int r = 0; r < 4; ++r) acc[nt][r] = 0.f;

        const int bh = b * NHEADS + jt;
        if (three < 2) {
            #pragma unroll
            for (int nt = 0; nt < 4; ++nt)
                #pragma unroll
                for (int kt = 0; kt < 8; ++kt) {
                    const bf16x8 bb = *(const bf16x8*)&Wt[(16 * nt + c) * 264 + kt * 32 + q4 * 8];
                    acc[nt] = __builtin_amdgcn_mfma_f32_16x16x32_bf16(aT[kt], bb, acc[nt], 0, 0, 0);
                }
            unsigned short* dst = (three == 0 ? q_bf : k_bf) + ((size_t)bh * NT + n0) * DH;
            const float sc = (three == 0) ? QSCALE : 1.0f;
            #pragma unroll
            for (int nt = 0; nt < 4; ++nt)
                #pragma unroll
                for (int r = 0; r < 4; ++r)
                    dst[(size_t)(16 * w + 4 * q4 + r) * DH + 16 * nt + c] = f2bf(acc[nt][r] * sc);
        } else {
            bf16x8 aW[8];
            #pragma unroll
            for (int kt = 0; kt < 8; ++kt)
                aW[kt] = *(const bf16x8*)&Wt[(16 * w + c) * 264 + kt * 32 + q4 * 8];
            #pragma unroll
            for (int nt = 0; nt < 4; ++nt)
                #pragma unroll
                for (int kt = 0; kt < 8; ++kt) {
                    const bf16x8 bb = *(const bf16x8*)&An[(16 * nt + c) * 264 + kt * 32 + q4 * 8];
                    acc[nt] = __builtin_amdgcn_mfma_f32_16x16x32_bf16(aW[kt], bb, acc[nt], 0, 0, 0);
                }
            unsigned short* dst = v_bf + (size_t)bh * DH * NT;
            #pragma unroll
            for (int nt = 0; nt < 4; ++nt)
                #pragma unroll
                for (int r = 0; r < 4; ++r)
                    dst[(size_t)(16 * w + 4 * q4 + r) * NT + n0 + 16 * nt + c] = f2bf(acc[nt][r]);
        }
    }
}

// ---------------------------------------------------------------------------
// Kernel 2: single-pass bf16-MFMA flash attention with ASYNC triple-buffered
// K/V staging (swizzled global_load_lds) and ONE fused
// "s_waitcnt vmcnt(4); s_barrier" per K-tile (next tile's DMA stays in
// flight across the barrier). Max-free softmax via exp2 (scale in q).
// grid = 16 bh * 32 qtiles = 512 blocks, 256 threads (4 waves, 32 q/wave).
// LDS: K 3*8KB + V 3*8KB + Ps(bf16 128x72) 18432 = 67584 B -> 2 blocks/CU.
// Swizzle: logical 16B-chunk (row, kc) stored at phys chunk row*8+(kc^(row&7));
// applied on the global SOURCE address so the DMA's lane*16B dest works.
// ---------------------------------------------------------------------------
__global__ __launch_bounds__(256, 2) void k_attn(
    const unsigned short* __restrict__ qg,  // [bh][n][d], pre-scaled by QSCALE
    const unsigned short* __restrict__ kg,  // [bh][n][d]
    const unsigned short* __restrict__ vg,  // [bh][d][n]  (transposed)
    unsigned short* __restrict__ o)         // [B][N][C] bf16
{
    __shared__ unsigned short Ks[3 * 4096];
    __shared__ unsigned short Vt[3 * 4096];
    __shared__ __bf16 Ps[128 * 72];

    const int bh   = blockIdx.x >> 5;          // 0..15
    const int n0   = (blockIdx.x & 31) << 7;   // 128-query tile base
    const int b    = bh >> 2;
    const int head = bh & 3;
    const int tid  = threadIdx.x;
    const int w    = tid >> 6;                 // wave -> query rows 32w..32w+31
    const int lane = tid & 63;
    const int q4   = lane >> 4;
    const int c    = lane & 15;

    const unsigned short* kb = kg + (size_t)bh * NT * DH;
    const unsigned short* vb = vg + (size_t)bh * DH * NT;

    // ---- Q A-frags direct from global ----
    bf16x8 aq[2][2];
    {
        const unsigned short* qp = qg + ((size_t)bh * NT + n0) * DH;
        #pragma unroll
        for (int g = 0; g < 2; ++g) {
            const unsigned short* qrow = qp + (size_t)(32 * w + 16 * g + c) * DH;
            aq[g][0] = *(const bf16x8*)(qrow + q4 * 8);
            aq[g][1] = *(const bf16x8*)(qrow + 32 + q4 * 8);
        }
    }

    // ---- staging lane geometry (per 1KB DMA instruction) ----
    const int rr = lane >> 3;                  // row within 8-row group
    const int kc = (lane & 7) ^ rr;            // swizzled 16B-chunk column
    // K global lane offset within a tile-group: row rr, chunk kc
    const int koffK = rr * DH + kc * 8;

    // ---- swizzled frag-read offsets ----
    const int sw0 = ((q4    ) ^ (c & 7)) * 8;  // chunk q4   of a 64-elem row
    const int sw1 = ((q4 + 4) ^ (c & 7)) * 8;  // chunk q4+4 (col offset 32)

    // issue one K/V tile's DMA for this wave into buffer bi
    #define ISSUE_TILE(it_, bi_)                                               \
        {                                                                      \
            const unsigned short* ktp = kb + (size_t)(it_) * 64 * DH;          \
            const unsigned short* vtp = vb + (size_t)(it_) * 64;               \
            _Pragma("unroll")                                                  \
            for (int t = 0; t < 2; ++t) {                                      \
                const int grp_ = w * 2 + t;                                    \
                gload16(ktp + grp_ * 512 + koffK,                              \
                        &Ks[(bi_) * 4096 + grp_ * 512 + lane * 8]);            \
                gload16(vtp + (size_t)(grp_ * 8 + rr) * NT + kc * 8,           \
                        &Vt[(bi_) * 4096 + grp_ * 512 + lane * 8]);            \
            }                                                                  \
        }

    ISSUE_TILE(0, 0)

    f32x4 oac[2][4];
    #pragma unroll
    for (int g = 0; g < 2; ++g)
        #pragma unroll
        for (int dt = 0; dt < 4; ++dt)
            #pragma unroll
            for (int r = 0; r < 4; ++r) oac[g][dt][r] = 0.f;
    float l_r[2][4] = {};

    int cur = 0, nxt = 1, nx2 = 2;
    for (int it = 0; it < 64; ++it) {
        if (it < 63) {
            ISSUE_TILE(it + 1, nxt)
            // own tile-it DMAs done (4 oldest of 8); all waves staged; prior
            // reads already consumed (lgkm waited before their MFMA uses).
            asm volatile("s_waitcnt vmcnt(4)\n\ts_barrier" ::: "memory");
        } else {
            asm volatile("s_waitcnt vmcnt(0)\n\ts_barrier" ::: "memory");
        }

        const unsigned short* Kb = &Ks[cur * 4096];
        const unsigned short* Vb = &Vt[cur * 4096];

        // ---- S = Q K^T for both row groups (K frags shared) ----
        f32x4 s[2][4];
        #pragma unroll
        for (int nt = 0; nt < 4; ++nt) {
            const bf16x8 b0 = *(const bf16x8*)&Kb[(16 * nt + c) * 64 + sw0];
            const bf16x8 b1 = *(const bf16x8*)&Kb[(16 * nt + c) * 64 + sw1];
            #pragma unroll
            for (int g = 0; g < 2; ++g) {
                f32x4 acc;
                #pragma unroll
                for (int r = 0; r < 4; ++r) acc[r] = 0.f;
                acc = __builtin_amdgcn_mfma_f32_16x16x32_bf16(aq[g][0], b0, acc, 0, 0, 0);
                acc = __builtin_amdgcn_mfma_f32_16x16x32_bf16(aq[g][1], b1, acc, 0, 0, 0);
                s[g][nt] = acc;
            }
        }

        // ---- P = exp2(S); l partials in regs; store P (bf16, HW cvt) ----
        #pragma unroll
        for (int g = 0; g < 2; ++g)
            #pragma unroll
            for (int nt = 0; nt < 4; ++nt)
                #pragma unroll
                for (int r = 0; r < 4; ++r) {
                    const float e = exp2f(s[g][nt][r]);
                    l_r[g][r] += e;
                    Ps[(32 * w + 16 * g + 4 * q4 + r) * 72 + 16 * nt + c] = (__bf16)e;
                }

        // ---- PV (V frags shared across groups; P read back as bf16) ----
        bf16x8 pa[2][2];
        #pragma unroll
        for (int g = 0; g < 2; ++g) {
            const __bf16* prow = &Ps[(32 * w + 16 * g + c) * 72];
            pa[g][0] = *(const bf16x8*)(prow + q4 * 8);
            pa[g][1] = *(const bf16x8*)(prow + 32 + q4 * 8);
        }
        #pragma unroll
        for (int dt = 0; dt < 4; ++dt) {
            const bf16x8 v0 = *(const bf16x8*)&Vb[(16 * dt + c) * 64 + sw0];
            const bf16x8 v1 = *(const bf16x8*)&Vb[(16 * dt + c) * 64 + sw1];
            #pragma unroll
            for (int g = 0; g < 2; ++g) {
                oac[g][dt] = __builtin_amdgcn_mfma_f32_16x16x32_bf16(pa[g][0], v0, oac[g][dt], 0, 0, 0);
                oac[g][dt] = __builtin_amdgcn_mfma_f32_16x16x32_bf16(pa[g][1], v1, oac[g][dt], 0, 0, 0);
            }
        }

        const int tmp = cur; cur = nxt; nxt = nx2; nx2 = tmp;
    }
    #undef ISSUE_TILE

    // ---- deferred l reduction across the 16 column-lanes ----
    float rinv[2][4];
    #pragma unroll
    for (int g = 0; g < 2; ++g)
        #pragma unroll
        for (int r = 0; r < 4; ++r) {
            float t = l_r[g][r];
            t += __shfl_xor(t, 1);
            t += __shfl_xor(t, 2);
            t += __shfl_xor(t, 4);
            t += __shfl_xor(t, 8);
            rinv[g][r] = 1.0f / t;
        }

    unsigned short* ob = o + ((size_t)b * NT + n0 + 32 * w) * NC + head * DH;
    #pragma unroll
    for (int g = 0; g < 2; ++g)
        #pragma unroll
        for (int dt = 0; dt < 4; ++dt)
            #pragma unroll
            for (int r = 0; r < 4; ++r)
                ob[(size_t)(16 * g + 4 * q4 + r) * NC + 16 * dt + c] =
                    f2bf(oac[g][dt][r] * rinv[g][r]);
}

// ---------------------------------------------------------------------------
// Kernel 3: output projection via bf16 MFMA. (unchanged)
// ---------------------------------------------------------------------------
__global__ __launch_bounds__(256) void k_proj(
    const unsigned short* __restrict__ o_bf,     // [B][N][256] bf16
    const unsigned short* __restrict__ wproj_bf, // [256][256] bf16
    const float* __restrict__ b_proj,
    float* __restrict__ out)                     // [B][C][N]
{
    __shared__ unsigned short Os[64 * 264];
    __shared__ unsigned short Ws[64 * 264];

    const int b   = blockIdx.x >> 6;
    const int n0  = (blockIdx.x & 63) << 6;
    const int cg0 = blockIdx.y << 6;
    const int tid = threadIdx.x;
    const int w   = tid >> 6;
    const int lane = tid & 63;
    const int q4  = lane >> 4;
    const int c   = lane & 15;

    stage_64x256(Os, o_bf + ((size_t)b * NT + n0) * NC, tid);
    stage_64x256(Ws, wproj_bf + (size_t)cg0 * NC, tid);
    __syncthreads();

    bf16x8 a[8];
    #pragma unroll
    for (int kt = 0; kt < 8; ++kt)
        a[kt] = *(const bf16x8*)&Ws[(16 * w + c) * 264 + kt * 32 + q4 * 8];

    f32x4 acc[4];
    #pragma unroll
    for (int nt = 0; nt < 4; ++nt)
        #pragma unroll
        for (int r = 0; r < 4; ++r) acc[nt][r] = 0.f;

    #pragma unroll
    for (int nt = 0; nt < 4; ++nt)
        #pragma unroll
        for (int kt = 0; kt < 8; ++kt) {
            const bf16x8 bb = *(const bf16x8*)&Os[(16 * nt + c) * 264 + kt * 32 + q4 * 8];
            acc[nt] = __builtin_amdgcn_mfma_f32_16x16x32_bf16(a[kt], bb, acc[nt], 0, 0, 0);
        }

    #pragma unroll
    for (int nt = 0; nt < 4; ++nt)
        #pragma unroll
        for (int r = 0; r < 4; ++r) {
            const int cg = cg0 + 16 * w + 4 * q4 + r;
            out[((size_t)b * NC + cg) * NT + n0 + 16 * nt + c] = acc[nt][r] + b_proj[cg];
        }
}

// ---------------------------------------------------------------------------
extern "C" void kernel_launch(void* const* d_in, const int* in_sizes, int n_in,
                              void* d_out, int out_size, void* d_ws, size_t ws_size,
                              hipStream_t stream)
{
    const float* x      = (const float*)d_in[0];
    const float* ln_g   = (const float*)d_in[1];
    const float* ln_b   = (const float*)d_in[2];
    const float* w_qkv  = (const float*)d_in[3];
    const float* w_proj = (const float*)d_in[4];
    const float* b_proj = (const float*)d_in[5];
    float* out = (float*)d_out;

    const size_t TEN = (size_t)NB * NHEADS * NT * DH;   // 4,194,304 elements

    unsigned short* ws16 = (unsigned short*)d_ws;
    unsigned short* q_bf    = ws16;
    unsigned short* k_bf    = ws16 + TEN;
    unsigned short* v_bf    = ws16 + 2 * TEN;
    unsigned short* o_bf    = ws16 + 3 * TEN;            // [B][N][256] bf16
    unsigned short* wqkv_t  = ws16 + 4 * TEN;            // [768][256]
    unsigned short* wproj_b = wqkv_t + 768 * 256;        // [256][256]

    k_prep<<<80, 256, 0, stream>>>(w_qkv, w_proj, wqkv_t, wproj_b);
    k_ln_qkv<<<dim3(NB * 64, 3), 256, 0, stream>>>(x, ln_g, ln_b, wqkv_t, q_bf, k_bf, v_bf);
    k_attn<<<16 * 32, 256, 0, stream>>>(q_bf, k_bf, v_bf, o_bf);
    k_proj<<<dim3(NB * 64, 4), 256, 0, stream>>>(o_bf, wproj_b, b_proj, out);
}

// Round 7
// 221.767 us; speedup vs baseline: 1.2440x; 1.0809x over previous
//
#include <hip/hip_runtime.h>
#include <math.h>

#define NB 4
#define NC 256
#define NHEADS 4
#define DH 64
#define NT 4096            // 64*64 tokens per batch
// q pre-scale with log2(e) folded in: exp(s/8) == exp2(s * QSCALE)
#define QSCALE (0.125f * 1.44269504088896f)

typedef __bf16  bf16x8 __attribute__((ext_vector_type(8)));
typedef __bf16  bf16x4 __attribute__((ext_vector_type(4)));
typedef float   f32x4  __attribute__((ext_vector_type(4)));
typedef short   s16x8  __attribute__((ext_vector_type(8)));

static __device__ __forceinline__ unsigned short f2bf(float f) {
    unsigned u = __float_as_uint(f);
    u = (u + 0x7fffu + ((u >> 16) & 1u)) >> 16;   // round-to-nearest-even
    return (unsigned short)u;
}

// async 16B/lane global -> LDS (DMA, no VGPR round-trip). LDS dest is
// wave-uniform base + lane*16; global src is per-lane.
static __device__ __forceinline__ void gload16(const unsigned short* g, unsigned short* l) {
    __builtin_amdgcn_global_load_lds((const __attribute__((address_space(1))) void*)g,
                                     (__attribute__((address_space(3))) void*)l, 16, 0, 0);
}

// Stage 64 rows x 256 bf16 (global row stride 256 elems) -> LDS stride 264.
static __device__ __forceinline__ void stage_64x256(
    unsigned short* __restrict__ lds, const unsigned short* __restrict__ g, int tid)
{
    #pragma unroll
    for (int chunk = 0; chunk < 8; ++chunk) {
        const int row = chunk * 8 + (tid >> 5);
        const int col = (tid & 31) * 8;
        *(s16x8*)&lds[row * 264 + col] = *(const s16x8*)&g[row * 256 + col];
    }
}

// ---------------------------------------------------------------------------
// Kernel 0: weight prep (unchanged).
// ---------------------------------------------------------------------------
__global__ __launch_bounds__(256) void k_prep(
    const float* __restrict__ wqkv, const float* __restrict__ wproj,
    unsigned short* __restrict__ wqkv_t, unsigned short* __restrict__ wproj_bf)
{
    const int id = blockIdx.x;
    const int tid = threadIdx.x;
    if (id < 48) {
        __shared__ float T[64][65];
        const int jt = id % 12, ct = id / 12;
        #pragma unroll
        for (int p = 0; p < 16; ++p) {
            const int idx = tid + (p << 8);
            const int r = idx >> 6, cl = idx & 63;
            T[r][cl] = wqkv[(size_t)(ct * 64 + r) * 768 + jt * 64 + cl];
        }
        __syncthreads();
        #pragma unroll
        for (int p = 0; p < 16; ++p) {
            const int idx = tid + (p << 8);
            const int r = idx >> 6, cl = idx & 63;
            wqkv_t[(size_t)(jt * 64 + r) * 256 + ct * 64 + cl] = f2bf(T[cl][r]);
        }
    } else {
        const int base = (id - 48) * 2048 + tid * 8;
        s16x8 v;
        #pragma unroll
        for (int j = 0; j < 8; ++j) v[j] = (short)f2bf(wproj[base + j]);
        *(s16x8*)&wproj_bf[base] = v;
    }
}

// ---------------------------------------------------------------------------
// Kernel 1: LayerNorm + QKV GEMM via bf16 MFMA. x read ONCE into registers
// (stats and An-build share the same per-thread channel partition).
// ---------------------------------------------------------------------------
__global__ __launch_bounds__(256) void k_ln_qkv(
    const float* __restrict__ x,       // [B][C][N]
    const float* __restrict__ ln_g,
    const float* __restrict__ ln_b,
    const unsigned short* __restrict__ wqkv_t,  // [768][256] bf16
    unsigned short* __restrict__ q_bf,
    unsigned short* __restrict__ k_bf,
    unsigned short* __restrict__ v_bf)
{
    __shared__ unsigned short An[64 * 264];
    __shared__ unsigned short Wt[64 * 264];
    __shared__ float red1[4][64], red2[4][64];
    __shared__ float mu_s[64], rs_s[64];

    const int b     = blockIdx.x >> 6;
    const int n0    = (blockIdx.x & 63) << 6;
    const int three = blockIdx.y;
    const int tid   = threadIdx.x;
    const int li    = tid & 63;
    const int grp   = tid >> 6;
    const int w     = grp;
    const int lane  = li;
    const int q4    = lane >> 4;
    const int c     = lane & 15;

    const float* xb = x + ((size_t)b * NC) * NT + n0 + li;

    // ---- read this thread's 64 channels once ----
    float xr[64];
    #pragma unroll
    for (int chunk = 0; chunk < 8; ++chunk)
        #pragma unroll
        for (int j = 0; j < 8; ++j)
            xr[chunk * 8 + j] = xb[(size_t)(chunk * 32 + grp * 8 + j) * NT];

    float s1 = 0.f, s2 = 0.f;
    #pragma unroll
    for (int i = 0; i < 64; ++i) { s1 += xr[i]; s2 += xr[i] * xr[i]; }
    red1[grp][li] = s1; red2[grp][li] = s2;
    __syncthreads();
    if (tid < 64) {
        const float t1 = red1[0][tid] + red1[1][tid] + red1[2][tid] + red1[3][tid];
        const float t2 = red2[0][tid] + red2[1][tid] + red2[2][tid] + red2[3][tid];
        const float mu  = t1 * (1.0f / NC);
        const float var = t2 * (1.0f / NC) - mu * mu;
        mu_s[tid] = mu;
        rs_s[tid] = rsqrtf(var + 1e-5f);
    }
    __syncthreads();
    const float mu = mu_s[li];
    const float rs = rs_s[li];

    #pragma unroll
    for (int chunk = 0; chunk < 8; ++chunk) {
        s16x8 pk;
        #pragma unroll
        for (int j = 0; j < 8; ++j) {
            const int ch = chunk * 32 + grp * 8 + j;
            const float vv = (xr[chunk * 8 + j] - mu) * rs * ln_g[ch] + ln_b[ch];
            pk[j] = (short)f2bf(vv);
        }
        *(s16x8*)&An[li * 264 + chunk * 32 + grp * 8] = pk;
    }
    __syncthreads();

    bf16x8 aT[8];
    if (three < 2) {
        #pragma unroll
        for (int kt = 0; kt < 8; ++kt)
            aT[kt] = *(const bf16x8*)&An[(16 * w + c) * 264 + kt * 32 + q4 * 8];
    }

    for (int jt = 0; jt < 4; ++jt) {
        __syncthreads();
        stage_64x256(Wt, wqkv_t + (size_t)(three * 256 + jt * 64) * 256, tid);
        __syncthreads();

        f32x4 acc[4];
        #pragma unroll
        for (int nt = 0; nt < 4; ++nt)
            #pragma unroll
            for (int r = 0; r < 4; ++r) acc[nt][r] = 0.f;

        const int bh = b * NHEADS + jt;
        if (three < 2) {
            #pragma unroll
            for (int nt = 0; nt < 4; ++nt)
                #pragma unroll
                for (int kt = 0; kt < 8; ++kt) {
                    const bf16x8 bb = *(const bf16x8*)&Wt[(16 * nt + c) * 264 + kt * 32 + q4 * 8];
                    acc[nt] = __builtin_amdgcn_mfma_f32_16x16x32_bf16(aT[kt], bb, acc[nt], 0, 0, 0);
                }
            unsigned short* dst = (three == 0 ? q_bf : k_bf) + ((size_t)bh * NT + n0) * DH;
            const float sc = (three == 0) ? QSCALE : 1.0f;
            #pragma unroll
            for (int nt = 0; nt < 4; ++nt)
                #pragma unroll
                for (int r = 0; r < 4; ++r)
                    dst[(size_t)(16 * w + 4 * q4 + r) * DH + 16 * nt + c] = f2bf(acc[nt][r] * sc);
        } else {
            bf16x8 aW[8];
            #pragma unroll
            for (int kt = 0; kt < 8; ++kt)
                aW[kt] = *(const bf16x8*)&Wt[(16 * w + c) * 264 + kt * 32 + q4 * 8];
            #pragma unroll
            for (int nt = 0; nt < 4; ++nt)
                #pragma unroll
                for (int kt = 0; kt < 8; ++kt) {
                    const bf16x8 bb = *(const bf16x8*)&An[(16 * nt + c) * 264 + kt * 32 + q4 * 8];
                    acc[nt] = __builtin_amdgcn_mfma_f32_16x16x32_bf16(aW[kt], bb, acc[nt], 0, 0, 0);
                }
            unsigned short* dst = v_bf + (size_t)bh * DH * NT;
            #pragma unroll
            for (int nt = 0; nt < 4; ++nt)
                #pragma unroll
                for (int r = 0; r < 4; ++r)
                    dst[(size_t)(16 * w + 4 * q4 + r) * NT + n0 + 16 * nt + c] = f2bf(acc[nt][r]);
        }
    }
}

// ---------------------------------------------------------------------------
// Kernel 2: bf16-MFMA flash attention, S^T formulation: the QK^T MFMA is
// issued as (A=K, B=Q) so each lane holds 4 CONSECUTIVE KEYS for one query
// -> P stores become ds_write_b64 (was 32 scalar b16). Async triple-buffered
// K/V staging (swizzled global_load_lds), one fused vmcnt(4);s_barrier per
// tile. Max-free softmax via exp2 (scale folded into q).
// grid = 16 bh * 32 qtiles = 512 blocks, 256 threads (4 waves, 32 q/wave).
// LDS: K 3*8KB + V 3*8KB + Ps(bf16 128x72) 18432 = 67584 B -> 2 blocks/CU.
// ---------------------------------------------------------------------------
__global__ __launch_bounds__(256, 2) void k_attn(
    const unsigned short* __restrict__ qg,  // [bh][n][d], pre-scaled by QSCALE
    const unsigned short* __restrict__ kg,  // [bh][n][d]
    const unsigned short* __restrict__ vg,  // [bh][d][n]  (transposed)
    unsigned short* __restrict__ o)         // [B][N][C] bf16
{
    __shared__ unsigned short Ks[3 * 4096];
    __shared__ unsigned short Vt[3 * 4096];
    __shared__ __bf16 Ps[128 * 72];

    const int bh   = blockIdx.x >> 5;          // 0..15
    const int n0   = (blockIdx.x & 31) << 7;   // 128-query tile base
    const int b    = bh >> 2;
    const int head = bh & 3;
    const int tid  = threadIdx.x;
    const int w    = tid >> 6;                 // wave -> query rows 32w..32w+31
    const int lane = tid & 63;
    const int q4   = lane >> 4;
    const int c    = lane & 15;

    const unsigned short* kb = kg + (size_t)bh * NT * DH;
    const unsigned short* vb = vg + (size_t)bh * DH * NT;

    // ---- Q frags direct from global (lane&15 = query, 8 d-elems each) ----
    bf16x8 aq[2][2];
    {
        const unsigned short* qp = qg + ((size_t)bh * NT + n0) * DH;
        #pragma unroll
        for (int g = 0; g < 2; ++g) {
            const unsigned short* qrow = qp + (size_t)(32 * w + 16 * g + c) * DH;
            aq[g][0] = *(const bf16x8*)(qrow + q4 * 8);
            aq[g][1] = *(const bf16x8*)(qrow + 32 + q4 * 8);
        }
    }

    // ---- staging lane geometry (per 1KB DMA instruction) ----
    const int rr = lane >> 3;                  // row within 8-row group
    const int kc = (lane & 7) ^ rr;            // swizzled 16B-chunk column
    const int koffK = rr * DH + kc * 8;

    // ---- swizzled frag-read offsets ----
    const int sw0 = ((q4    ) ^ (c & 7)) * 8;  // chunk q4   (d 0..31)
    const int sw1 = ((q4 + 4) ^ (c & 7)) * 8;  // chunk q4+4 (d 32..63)

    #define ISSUE_TILE(it_, bi_)                                               \
        {                                                                      \
            const unsigned short* ktp = kb + (size_t)(it_) * 64 * DH;          \
            const unsigned short* vtp = vb + (size_t)(it_) * 64;               \
            _Pragma("unroll")                                                  \
            for (int t = 0; t < 2; ++t) {                                      \
                const int grp_ = w * 2 + t;                                    \
                gload16(ktp + grp_ * 512 + koffK,                              \
                        &Ks[(bi_) * 4096 + grp_ * 512 + lane * 8]);            \
                gload16(vtp + (size_t)(grp_ * 8 + rr) * NT + kc * 8,           \
                        &Vt[(bi_) * 4096 + grp_ * 512 + lane * 8]);            \
            }                                                                  \
        }

    ISSUE_TILE(0, 0)

    f32x4 oac[2][4];
    #pragma unroll
    for (int g = 0; g < 2; ++g)
        #pragma unroll
        for (int dt = 0; dt < 4; ++dt)
            #pragma unroll
            for (int r = 0; r < 4; ++r) oac[g][dt][r] = 0.f;
    float lsum[2][4] = {};   // per-lane l partials (query c, keys {16nt+4q4+r})

    int cur = 0, nxt = 1, nx2 = 2;
    for (int it = 0; it < 64; ++it) {
        if (it < 63) {
            ISSUE_TILE(it + 1, nxt)
            asm volatile("s_waitcnt vmcnt(4)\n\ts_barrier" ::: "memory");
        } else {
            asm volatile("s_waitcnt vmcnt(0)\n\ts_barrier" ::: "memory");
        }

        const unsigned short* Kb = &Ks[cur * 4096];
        const unsigned short* Vb = &Vt[cur * 4096];

        // ---- S^T = K Q^T: A = K-frag (m=key), B = Q-frag (n=query).
        //      D: col(lane&15)=query c, rows 4q4+r = keys 16nt+4q4+r ----
        f32x4 st[2][4];
        #pragma unroll
        for (int nt = 0; nt < 4; ++nt) {
            const bf16x8 kf0 = *(const bf16x8*)&Kb[(16 * nt + c) * 64 + sw0];
            const bf16x8 kf1 = *(const bf16x8*)&Kb[(16 * nt + c) * 64 + sw1];
            #pragma unroll
            for (int g = 0; g < 2; ++g) {
                f32x4 acc;
                #pragma unroll
                for (int r = 0; r < 4; ++r) acc[r] = 0.f;
                acc = __builtin_amdgcn_mfma_f32_16x16x32_bf16(kf0, aq[g][0], acc, 0, 0, 0);
                acc = __builtin_amdgcn_mfma_f32_16x16x32_bf16(kf1, aq[g][1], acc, 0, 0, 0);
                st[g][nt] = acc;
            }
        }

        // ---- P = exp2(S); pack 4 consecutive keys -> one ds_write_b64 ----
        #pragma unroll
        for (int g = 0; g < 2; ++g)
            #pragma unroll
            for (int nt = 0; nt < 4; ++nt) {
                bf16x4 pk;
                #pragma unroll
                for (int r = 0; r < 4; ++r) {
                    const float e = exp2f(st[g][nt][r]);
                    lsum[g][nt] += e;
                    pk[r] = (__bf16)e;
                }
                *(bf16x4*)&Ps[(32 * w + 16 * g + c) * 72 + 16 * nt + 4 * q4] = pk;
            }

        // ---- PV: A = P (m=query, b128 rows), B = V^T frags (shared) ----
        bf16x8 pa[2][2];
        #pragma unroll
        for (int g = 0; g < 2; ++g) {
            const __bf16* prow = &Ps[(32 * w + 16 * g + c) * 72];
            pa[g][0] = *(const bf16x8*)(prow + q4 * 8);
            pa[g][1] = *(const bf16x8*)(prow + 32 + q4 * 8);
        }
        #pragma unroll
        for (int dt = 0; dt < 4; ++dt) {
            const bf16x8 v0 = *(const bf16x8*)&Vb[(16 * dt + c) * 64 + sw0];
            const bf16x8 v1 = *(const bf16x8*)&Vb[(16 * dt + c) * 64 + sw1];
            #pragma unroll
            for (int g = 0; g < 2; ++g) {
                oac[g][dt] = __builtin_amdgcn_mfma_f32_16x16x32_bf16(pa[g][0], v0, oac[g][dt], 0, 0, 0);
                oac[g][dt] = __builtin_amdgcn_mfma_f32_16x16x32_bf16(pa[g][1], v1, oac[g][dt], 0, 0, 0);
            }
        }

        const int tmp = cur; cur = nxt; nxt = nx2; nx2 = tmp;
    }
    #undef ISSUE_TILE

    // ---- l: finish per-query sums (lanes with same c hold disjoint key
    //      subsets -> xor16+xor32), then redistribute to C/D row owners ----
    float rinv[2][4];
    #pragma unroll
    for (int g = 0; g < 2; ++g) {
        float t = (lsum[g][0] + lsum[g][1]) + (lsum[g][2] + lsum[g][3]);
        t += __shfl_xor(t, 16);
        t += __shfl_xor(t, 32);
        // lane holds l(query 32w+16g+c); epilogue row 4q4+r needs query 4q4+r
        #pragma unroll
        for (int r = 0; r < 4; ++r)
            rinv[g][r] = 1.0f / __shfl(t, 4 * q4 + r);
    }

    unsigned short* ob = o + ((size_t)b * NT + n0 + 32 * w) * NC + head * DH;
    #pragma unroll
    for (int g = 0; g < 2; ++g)
        #pragma unroll
        for (int dt = 0; dt < 4; ++dt)
            #pragma unroll
            for (int r = 0; r < 4; ++r)
                ob[(size_t)(16 * g + 4 * q4 + r) * NC + 16 * dt + c] =
                    f2bf(oac[g][dt][r] * rinv[g][r]);
}

// ---------------------------------------------------------------------------
// Kernel 3: output projection via bf16 MFMA. (unchanged)
// ---------------------------------------------------------------------------
__global__ __launch_bounds__(256) void k_proj(
    const unsigned short* __restrict__ o_bf,     // [B][N][256] bf16
    const unsigned short* __restrict__ wproj_bf, // [256][256] bf16
    const float* __restrict__ b_proj,
    float* __restrict__ out)                     // [B][C][N]
{
    __shared__ unsigned short Os[64 * 264];
    __shared__ unsigned short Ws[64 * 264];

    const int b   = blockIdx.x >> 6;
    const int n0  = (blockIdx.x & 63) << 6;
    const int cg0 = blockIdx.y << 6;
    const int tid = threadIdx.x;
    const int w   = tid >> 6;
    const int lane = tid & 63;
    const int q4  = lane >> 4;
    const int c   = lane & 15;

    stage_64x256(Os, o_bf + ((size_t)b * NT + n0) * NC, tid);
    stage_64x256(Ws, wproj_bf + (size_t)cg0 * NC, tid);
    __syncthreads();

    bf16x8 a[8];
    #pragma unroll
    for (int kt = 0; kt < 8; ++kt)
        a[kt] = *(const bf16x8*)&Ws[(16 * w + c) * 264 + kt * 32 + q4 * 8];

    f32x4 acc[4];
    #pragma unroll
    for (int nt = 0; nt < 4; ++nt)
        #pragma unroll
        for (int r = 0; r < 4; ++r) acc[nt][r] = 0.f;

    #pragma unroll
    for (int nt = 0; nt < 4; ++nt)
        #pragma unroll
        for (int kt = 0; kt < 8; ++kt) {
            const bf16x8 bb = *(const bf16x8*)&Os[(16 * nt + c) * 264 + kt * 32 + q4 * 8];
            acc[nt] = __builtin_amdgcn_mfma_f32_16x16x32_bf16(a[kt], bb, acc[nt], 0, 0, 0);
        }

    #pragma unroll
    for (int nt = 0; nt < 4; ++nt)
        #pragma unroll
        for (int r = 0; r < 4; ++r) {
            const int cg = cg0 + 16 * w + 4 * q4 + r;
            out[((size_t)b * NC + cg) * NT + n0 + 16 * nt + c] = acc[nt][r] + b_proj[cg];
        }
}

// ---------------------------------------------------------------------------
extern "C" void kernel_launch(void* const* d_in, const int* in_sizes, int n_in,
                              void* d_out, int out_size, void* d_ws, size_t ws_size,
                              hipStream_t stream)
{
    const float* x      = (const float*)d_in[0];
    const float* ln_g   = (const float*)d_in[1];
    const float* ln_b   = (const float*)d_in[2];
    const float* w_qkv  = (const float*)d_in[3];
    const float* w_proj = (const float*)d_in[4];
    const float* b_proj = (const float*)d_in[5];
    float* out = (float*)d_out;

    const size_t TEN = (size_t)NB * NHEADS * NT * DH;   // 4,194,304 elements

    unsigned short* ws16 = (unsigned short*)d_ws;
    unsigned short* q_bf    = ws16;
    unsigned short* k_bf    = ws16 + TEN;
    unsigned short* v_bf    = ws16 + 2 * TEN;
    unsigned short* o_bf    = ws16 + 3 * TEN;            // [B][N][256] bf16
    unsigned short* wqkv_t  = ws16 + 4 * TEN;            // [768][256]
    unsigned short* wproj_b = wqkv_t + 768 * 256;        // [256][256]

    k_prep<<<80, 256, 0, stream>>>(w_qkv, w_proj, wqkv_t, wproj_b);
    k_ln_qkv<<<dim3(NB * 64, 3), 256, 0, stream>>>(x, ln_g, ln_b, wqkv_t, q_bf, k_bf, v_bf);
    k_attn<<<16 * 32, 256, 0, stream>>>(q_bf, k_bf, v_bf, o_bf);
    k_proj<<<dim3(NB * 64, 4), 256, 0, stream>>>(o_bf, wproj_b, b_proj, out);
}